// Round 2
// baseline (530.211 us; speedup 1.0000x reference)
//
#include <hip/hip_runtime.h>

// Side Window Filter — bit-exact vs harness np ref (absmax 0.0 contract).
// Math contract (DO NOT REORDER): per output, each of the 8 windows is a
// sequential __builtin_fmaf chain over its taps in row-major (i,j) order,
// fp32 accumulator starting at 0, weights fp32(1/15), fp32(1/9); replicate
// boundary; 8 iterations; fp32 iterates; fp32 d/argmin(first-idx)/update;
// final clip(|x0-res|,0,255).
//
// R12: block-cooperative LDS staging. 128-thread block owns 512 output
// columns x 8 output rows. It stages 12 source rows x 532 floats into LDS
// (25.5 KB -> 6 blocks/CU) with replicate clamping FOLDED INTO THE HALO:
// LDS[p<0] = src[((p%3)+3)%3], LDS[p>=WC] = src[(W-1)*3 + p%3] — taps only
// leave the image by whole pixels with channel preserved, so the unclamped
// fast-path indexing reads exactly the clamped tap. No divergent edge path.
// One __syncthreads, then 8 output rows of pure compute: 5 ds_read_b128
// per window row (lane-linear, conflict-free), identical fma chain.
// t-loop kept rolled so the hot body stays ~2.5 KB (I-cache resident).

static constexpr int H     = 2048;
static constexpr int W     = 2048;
static constexpr int C     = 3;
static constexpr int WC    = W * C;        // 6144 floats per row
static constexpr int RPT   = 8;            // output rows per block
static constexpr int TPB   = 128;          // threads per block (2 waves)
static constexpr int BCOLS = TPB * 4;      // 512 output floats per block
static constexpr int RW    = BCOLS + 20;   // 532 staged floats per row
static constexpr int NROWS = RPT + 4;      // 12 staged rows
static constexpr int NCH   = RW / 4;       // 133 float4 chunks per row

template<bool FINAL>
__global__ __launch_bounds__(TPB)
void swf_lds(const float* __restrict__ src, float* __restrict__ dst,
             const float* __restrict__ x0) {
  __shared__ __align__(16) float s[NROWS][RW];

  const int tid  = threadIdx.x;
  const int bx   = blockIdx.x;
  const int y0   = blockIdx.y * RPT;
  const int base = bx * BCOLS - 8;       // global float idx of LDS col 0

  // ---- stage 12 rows (vertical replicate via hy clamp; horizontal
  //      replicate folded into halo values) ----
  for (int r = 0; r < NROWS; ++r) {
    int hy = y0 + r - 2;
    hy = hy < 0 ? 0 : (hy > H - 1 ? H - 1 : hy);
    const float* srow = src + (size_t)hy * WC;
    for (int cc = tid; cc < NCH; cc += TPB) {
      const int gp = base + cc * 4;
      float4 v;
      if (gp >= 0 && gp + 3 < WC) {
        v = *(const float4*)(srow + gp);
      } else {
        float tmp[4];
#pragma unroll
        for (int u = 0; u < 4; ++u) {
          const int f = gp + u;
          const int idx = (f < 0)    ? ((f % 3) + 3) % 3
                        : (f >= WC)  ? (W - 1) * 3 + (f % 3)
                        : f;
          tmp[u] = srow[idx];
        }
        v.x = tmp[0]; v.y = tmp[1]; v.z = tmp[2]; v.w = tmp[3];
      }
      *(float4*)&s[r][cc * 4] = v;
    }
  }
  __syncthreads();

  const float w15 = 1.0f / 15.0f;   // fp32(1/15)
  const float w9  = 1.0f / 9.0f;    // fp32(1/9)
  const int   lc   = tid * 4;               // LDS float idx of window start
  const int   col4 = bx * BCOLS + tid * 4;  // global output float idx

#pragma unroll 1
  for (int t = 0; t < RPT; ++t) {
    float acc[4][8];
#pragma unroll
    for (int k = 0; k < 4; ++k)
#pragma unroll
      for (int m = 0; m < 8; ++m) acc[k][m] = 0.0f;
    float center[4];

#pragma unroll
    for (int i = 0; i < 5; ++i) {
      const float* row = &s[t + i][lc];
      const float4 q0 = *(const float4*)(row);
      const float4 q1 = *(const float4*)(row + 4);
      const float4 q2 = *(const float4*)(row + 8);
      const float4 q3 = *(const float4*)(row + 12);
      const float4 q4 = *(const float4*)(row + 16);
      const float r[20] = {q0.x,q0.y,q0.z,q0.w, q1.x,q1.y,q1.z,q1.w,
                           q2.x,q2.y,q2.z,q2.w, q3.x,q3.y,q3.z,q3.w,
                           q4.x,q4.y,q4.z,q4.w};
#pragma unroll
      for (int k = 0; k < 4; ++k) {
        // tap j of output col4+k -> r[k + 3j + 2]
        const float t0 = r[k+2], t1 = r[k+5], t2 = r[k+8],
                    t3 = r[k+11], t4 = r[k+14];
        float* a = acc[k];
        if (i == 2) center[k] = t2;
        // L: cols 0..2, all rows
        a[0]=__builtin_fmaf(w15,t0,a[0]); a[0]=__builtin_fmaf(w15,t1,a[0]); a[0]=__builtin_fmaf(w15,t2,a[0]);
        // R: cols 2..4, all rows
        a[1]=__builtin_fmaf(w15,t2,a[1]); a[1]=__builtin_fmaf(w15,t3,a[1]); a[1]=__builtin_fmaf(w15,t4,a[1]);
        if (i <= 2) {  // U: rows 0..2, all cols
          a[2]=__builtin_fmaf(w15,t0,a[2]); a[2]=__builtin_fmaf(w15,t1,a[2]); a[2]=__builtin_fmaf(w15,t2,a[2]);
          a[2]=__builtin_fmaf(w15,t3,a[2]); a[2]=__builtin_fmaf(w15,t4,a[2]);
          // NW / NE
          a[4]=__builtin_fmaf(w9,t0,a[4]); a[4]=__builtin_fmaf(w9,t1,a[4]); a[4]=__builtin_fmaf(w9,t2,a[4]);
          a[5]=__builtin_fmaf(w9,t2,a[5]); a[5]=__builtin_fmaf(w9,t3,a[5]); a[5]=__builtin_fmaf(w9,t4,a[5]);
        }
        if (i >= 2) {  // D: rows 2..4, all cols
          a[3]=__builtin_fmaf(w15,t0,a[3]); a[3]=__builtin_fmaf(w15,t1,a[3]); a[3]=__builtin_fmaf(w15,t2,a[3]);
          a[3]=__builtin_fmaf(w15,t3,a[3]); a[3]=__builtin_fmaf(w15,t4,a[3]);
          // SW / SE
          a[6]=__builtin_fmaf(w9,t0,a[6]); a[6]=__builtin_fmaf(w9,t1,a[6]); a[6]=__builtin_fmaf(w9,t2,a[6]);
          a[7]=__builtin_fmaf(w9,t2,a[7]); a[7]=__builtin_fmaf(w9,t3,a[7]); a[7]=__builtin_fmaf(w9,t4,a[7]);
        }
      }
    }

    // epilogue for output row y0+t: fp32 d/argmin/update, float4 store
    const int y = y0 + t;
    float4 xv4;
    if (FINAL) xv4 = *(const float4*)(x0 + (size_t)y * WC + col4);
    float o[4];
#pragma unroll
    for (int k = 0; k < 4; ++k) {
      float best  = acc[k][0] - center[k];
      float besta = fabsf(best);
#pragma unroll
      for (int m = 1; m < 8; ++m) {
        const float d = acc[k][m] - center[k];
        const float a = fabsf(d);
        if (a < besta) { besta = a; best = d; }
      }
      const float res = center[k] + best;
      if (FINAL) {
        const float xv = (k == 0) ? xv4.x : (k == 1) ? xv4.y
                       : (k == 2) ? xv4.z : xv4.w;
        float diff = fabsf(xv - res);
        o[k] = diff > 255.0f ? 255.0f : diff;
      } else {
        o[k] = res;
      }
    }
    float4 ov;
    ov.x = o[0]; ov.y = o[1]; ov.z = o[2]; ov.w = o[3];
    *(float4*)(dst + (size_t)y * WC + col4) = ov;
  }
}

extern "C" void kernel_launch(void* const* d_in, const int* in_sizes, int n_in,
                              void* d_out, int out_size, void* d_ws, size_t ws_size,
                              hipStream_t stream) {
  const float* x0  = (const float*)d_in[0];
  float*       out = (float*)d_out;
  float*       ws  = (float*)d_ws;   // needs H*W*C*4 = 50.3 MB

  dim3 grid(WC / BCOLS, H / RPT);    // 12 x-blocks, 256 y-blocks
  dim3 block(TPB);

  swf_lds<false><<<grid, block, 0, stream>>>(x0,  ws,  nullptr);  // iter 1
  swf_lds<false><<<grid, block, 0, stream>>>(ws,  out, nullptr);  // iter 2
  swf_lds<false><<<grid, block, 0, stream>>>(out, ws,  nullptr);  // iter 3
  swf_lds<false><<<grid, block, 0, stream>>>(ws,  out, nullptr);  // iter 4
  swf_lds<false><<<grid, block, 0, stream>>>(out, ws,  nullptr);  // iter 5
  swf_lds<false><<<grid, block, 0, stream>>>(ws,  out, nullptr);  // iter 6
  swf_lds<false><<<grid, block, 0, stream>>>(out, ws,  nullptr);  // iter 7
  swf_lds<true ><<<grid, block, 0, stream>>>(ws,  out, x0);       // iter 8 + diff
}